// Round 1
// baseline (143.485 us; speedup 1.0000x reference)
//
#include <hip/hip_runtime.h>
#include <math.h>

#define THREADS 256

// Combine two online-softmax partial states (m1,s1) <- (m1,s1) ⊕ (m2,s2)
__device__ __forceinline__ void combine_ms(float& m, float& s, float m2, float s2) {
    float nm = fmaxf(m, m2);
    if (nm == -INFINITY) { m = nm; s = 0.0f; return; }   // both empty: avoid inf-inf = NaN
    s = s * __expf(m - nm) + s2 * __expf(m2 - nm);
    m = nm;
}

__global__ __launch_bounds__(THREADS)
void ce_nll_kernel(const float* __restrict__ logits,
                   const int*   __restrict__ target,
                   float*       __restrict__ out,
                   int C) {
    const int n   = blockIdx.x;
    const int tid = threadIdx.x;
    const float* row = logits + (size_t)n * (size_t)C;

    // Row base is only guaranteed 4B-aligned (C*4 = 201028 B, %16 != 0 for odd n).
    // Scalar lead-in until 16B alignment, then float4 body, then scalar tail.
    uintptr_t addr = (uintptr_t)row;
    int mis  = (int)((addr >> 2) & 3);     // misalignment in floats (0..3)
    int lead = (4 - mis) & 3;
    if (lead > C) lead = C;
    const int rem  = C - lead;
    const int nvec = rem >> 2;
    const int tail = rem & 3;

    float m = -INFINITY, s = 0.0f;

    // lead scalars (threads 0..lead-1)
    if (tid < lead) { m = row[tid]; s = 1.0f; }          // combine(-inf,0,v) == (v,1)

    // vectorized body: coalesced 16B/lane, grid of threads strides the row
    const float4* vrow = (const float4*)(row + lead);
    for (int i = tid; i < nvec; i += THREADS) {
        float4 v = vrow[i];
        float vm = fmaxf(fmaxf(v.x, v.y), fmaxf(v.z, v.w));
        float nm = fmaxf(m, vm);
        // 5 exps per 4 elements (exp(m-nm) rescale + 4 element exps)
        s = s * __expf(m - nm)
            + __expf(v.x - nm) + __expf(v.y - nm)
            + __expf(v.z - nm) + __expf(v.w - nm);
        m = nm;
    }

    // tail scalars (threads 0..tail-1)
    if (tid < tail) {
        float v  = row[lead + (nvec << 2) + tid];
        float nm = fmaxf(m, v);
        s = s * __expf(m - nm) + __expf(v - nm);
        m = nm;
    }

    // wave-level butterfly reduce (64 lanes)
    #pragma unroll
    for (int off = 32; off > 0; off >>= 1) {
        float m2 = __shfl_xor(m, off, 64);
        float s2 = __shfl_xor(s, off, 64);
        combine_ms(m, s, m2, s2);
    }

    // cross-wave reduce via LDS (4 waves)
    __shared__ float sm[THREADS / 64], ss[THREADS / 64];
    const int wid  = tid >> 6;
    const int lane = tid & 63;
    if (lane == 0) { sm[wid] = m; ss[wid] = s; }
    __syncthreads();

    if (tid == 0) {
        #pragma unroll
        for (int w = 1; w < THREADS / 64; ++w) combine_ms(m, s, sm[w], ss[w]);
        const int t  = target[n];
        const float lt = row[t];                 // L2-warm after the streaming pass
        out[n] = (m + __logf(s)) - lt;           // nll = logsumexp - logit_target
    }
}

extern "C" void kernel_launch(void* const* d_in, const int* in_sizes, int n_in,
                              void* d_out, int out_size, void* d_ws, size_t ws_size,
                              hipStream_t stream) {
    const float* logits = (const float*)d_in[0];
    const int*   target = (const int*)d_in[1];
    float*       out    = (float*)d_out;

    const int N = out_size;                      // 4096 rows
    const int C = in_sizes[0] / N;               // 50257 classes

    ce_nll_kernel<<<N, THREADS, 0, stream>>>(logits, target, out, C);
}